// Round 1
// baseline (29.104 us; speedup 1.0000x reference)
//
#include <hip/hip_runtime.h>
#include <math.h>

#define NQ      10
#define NSTATE  1024   // 2^NQ
#define NLAYERS 4
#define IDIM    768
#define BLK     512

// One block per batch element. State as separate re/im fp32 arrays in LDS,
// double-buffered for the CNOT-ring permutation step.
//
// Wire w <-> bit (9-w) of the flattened amplitude index (row-major (2,)*10).
// Layer structure exploited:
//   - embedding RY merged into layer-0 RY (same-axis rotations add)
//   - RY+RZ per wire fused into one pair update (single barrier per wire)
//   - the 10-CNOT ring is one GF(2)-linear permutation: prefix-XOR from MSB.
__global__ __launch_bounds__(BLK) void qhead_kernel(
    const float* __restrict__ x,    // [B, 768]
    const float* __restrict__ Wr,   // [10, 768]
    const float* __restrict__ br,   // [10]
    const float* __restrict__ wts,  // [4, 10, 2]
    const float* __restrict__ Wo,   // [1, 10]
    const float* __restrict__ bo,   // [1]
    float* __restrict__ out,        // [B]
    int B)
{
    __shared__ float buf[2][2][NSTATE];      // [buffer][re/im][amp]  16 KB
    __shared__ float sx[IDIM];               // staged x row           3 KB
    __shared__ float sAng[NQ];
    __shared__ float sTrig[NLAYERS][NQ][4];  // cy, sy, cz, sz
    __shared__ float sWo[NQ];
    __shared__ float sRed[BLK / 64];

    const int b    = blockIdx.x;
    const int t    = threadIdx.x;
    const int lane = t & 63;
    const int wid  = t >> 6;

    // ---- stage x row, Wo, init state |0...0> ----
    for (int k = t; k < IDIM; k += BLK) sx[k] = x[b * IDIM + k];
    if (t < NQ) sWo[t] = Wo[t];
    buf[0][0][t]       = (t == 0) ? 1.f : 0.f;
    buf[0][0][t + 512] = 0.f;
    buf[0][1][t]       = 0.f;
    buf[0][1][t + 512] = 0.f;
    __syncthreads();

    // ---- embedding angles: wave `wid` handles qubits wid, wid+8 ----
    for (int q = wid; q < NQ; q += 8) {
        float s = 0.f;
        #pragma unroll
        for (int j = 0; j < IDIM / 64; ++j) {
            const int k = lane + 64 * j;
            s = fmaf(sx[k], Wr[q * IDIM + k], s);
        }
        #pragma unroll
        for (int off = 32; off; off >>= 1) s += __shfl_xor(s, off, 64);
        if (lane == 0)
            sAng[q] = tanhf(s + br[q]) * 1.57079632679489662f;  // * pi/2
    }
    __syncthreads();

    // ---- trig precompute (layer-0 RY absorbs embedding angle) ----
    if (t < NLAYERS * NQ) {
        const int l = t / NQ, w = t % NQ;
        const float th = wts[(l * NQ + w) * 2 + 0] + (l == 0 ? sAng[w] : 0.f);
        const float ph = wts[(l * NQ + w) * 2 + 1];
        sTrig[l][w][0] = cosf(0.5f * th);
        sTrig[l][w][1] = sinf(0.5f * th);
        sTrig[l][w][2] = cosf(0.5f * ph);
        sTrig[l][w][3] = sinf(0.5f * ph);
    }
    __syncthreads();

    // ---- 4 layers: 10 fused RY+RZ pair-updates + 1 CNOT-ring permutation ----
    int cur = 0;
    for (int l = 0; l < NLAYERS; ++l) {
        for (int w = 0; w < NQ; ++w) {
            const int   bit = 9 - w;
            const float cy = sTrig[l][w][0], sy = sTrig[l][w][1];
            const float cz = sTrig[l][w][2], sz = sTrig[l][w][3];
            const int i0 = ((t >> bit) << (bit + 1)) | (t & ((1 << bit) - 1));
            const int i1 = i0 | (1 << bit);
            const float a0r = buf[cur][0][i0], a0i = buf[cur][1][i0];
            const float a1r = buf[cur][0][i1], a1i = buf[cur][1][i1];
            // RY
            const float t0r = cy * a0r - sy * a1r, t0i = cy * a0i - sy * a1i;
            const float t1r = sy * a0r + cy * a1r, t1i = sy * a0i + cy * a1i;
            // RZ: amp0 *= (cz - i sz), amp1 *= (cz + i sz)
            buf[cur][0][i0] = cz * t0r + sz * t0i;
            buf[cur][1][i0] = cz * t0i - sz * t0r;
            buf[cur][0][i1] = cz * t1r - sz * t1i;
            buf[cur][1][i1] = cz * t1i + sz * t1r;
            __syncthreads();
        }
        // CNOT ring as one permutation: dst[pi(i)] = src[i]
        // pi: wire w>=1 -> XOR of wires 0..w (prefix-XOR from MSB side);
        //     wire 0   -> XOR of wires 1..9
        const int nxt = cur ^ 1;
        #pragma unroll
        for (int h = 0; h < 2; ++h) {
            const int i = t + h * 512;
            unsigned y = (unsigned)i;
            y ^= y >> 1; y ^= y >> 2; y ^= y >> 4; y ^= y >> 8;
            const unsigned j =
                (y & 511u) | (((y ^ (unsigned)(i >> 9)) & 1u) << 9);
            buf[nxt][0][j] = buf[cur][0][i];
            buf[nxt][1][j] = buf[cur][1][i];
        }
        cur = nxt;
        __syncthreads();
    }

    // ---- expvals folded into head: logit = sum_i p_i * g_i + bo ----
    float acc = 0.f;
    #pragma unroll
    for (int h = 0; h < 2; ++h) {
        const int i = t + h * 512;
        const float re = buf[cur][0][i], im = buf[cur][1][i];
        const float p = re * re + im * im;
        float g = 0.f;
        #pragma unroll
        for (int w = 0; w < NQ; ++w)
            g += ((i >> (9 - w)) & 1) ? -sWo[w] : sWo[w];
        acc = fmaf(p, g, acc);
    }
    #pragma unroll
    for (int off = 32; off; off >>= 1) acc += __shfl_xor(acc, off, 64);
    if (lane == 0) sRed[wid] = acc;
    __syncthreads();
    if (t == 0) {
        float tot = 0.f;
        #pragma unroll
        for (int w = 0; w < BLK / 64; ++w) tot += sRed[w];
        const float logit = tot + bo[0];
        out[b] = 1.f / (1.f + expf(-logit));
    }
}

extern "C" void kernel_launch(void* const* d_in, const int* in_sizes, int n_in,
                              void* d_out, int out_size, void* d_ws, size_t ws_size,
                              hipStream_t stream) {
    const float* x   = (const float*)d_in[0];
    const float* Wr  = (const float*)d_in[1];
    const float* br  = (const float*)d_in[2];
    const float* wts = (const float*)d_in[3];
    const float* Wo  = (const float*)d_in[4];
    const float* bo  = (const float*)d_in[5];
    float* out = (float*)d_out;
    const int B = in_sizes[0] / IDIM;  // 1024

    qhead_kernel<<<B, BLK, 0, stream>>>(x, Wr, br, wts, Wo, bo, out, B);
}

// Round 2
// 24.955 us; speedup vs baseline: 1.1663x; 1.1663x over previous
//
#include <hip/hip_runtime.h>
#include <math.h>

#define NQ      10
#define NLAYERS 4
#define IDIM    768

// ---------------------------------------------------------------------------
// Compile-time circuit plan.
//
// Index bit b (0..9) <-> wire w = 9-b (row-major (2,)*10 flattening).
// One CNOT ring (CNOT(w,(w+1)%10), w=0..9) maps amplitude index i -> pi(i),
// a GF(2)-linear invertible map P. We never permute data; instead, after l
// rings the logical index of storage slot x is u = P^l x. A rotation gate on
// logical bit b therefore pairs slots differing by mask m = P^-l e_b, and the
// "which side is |0>" parity is row_b(P^l) . x. The Z-readout after 4 rings
// uses rows of P^4. All masks/rows are compile-time constants.
// ---------------------------------------------------------------------------
struct Plan {
    unsigned short mask[NLAYERS][NQ];
    unsigned short row [NLAYERS][NQ];
    unsigned short zrow[NQ];
};

constexpr int cpop(unsigned v) { int c = 0; for (; v; v >>= 1) c += (int)(v & 1u); return c; }

constexpr Plan make_plan() {
    // P (ring) and Q = P^-1, as rows: out_b = parity(row[b] & x)
    unsigned P[NQ] = {}, Q[NQ] = {};
    for (int b = 0; b < NQ; ++b) { P[b] = 1u << b; Q[b] = 1u << b; }
    for (int w = 0; w < NQ; ++w) {               // pi = C9 ∘ ... ∘ C0
        const int c = (NQ - 1) - w, t = (NQ - 1) - ((w + 1) % NQ);
        P[t] ^= P[c];
    }
    for (int w = NQ - 1; w >= 0; --w) {          // pi^-1 = C0 ∘ ... ∘ C9
        const int c = (NQ - 1) - w, t = (NQ - 1) - ((w + 1) % NQ);
        Q[t] ^= Q[c];
    }
    // powers P^l (l=0..4) and Q^l (l=0..3)
    unsigned Pl[NLAYERS + 1][NQ] = {}, Ql[NLAYERS][NQ] = {};
    for (int b = 0; b < NQ; ++b) { Pl[0][b] = 1u << b; Ql[0][b] = 1u << b; }
    for (int l = 1; l <= NLAYERS; ++l)
        for (int i = 0; i < NQ; ++i) {
            unsigned r = 0;
            for (int j = 0; j < NQ; ++j) if ((P[i] >> j) & 1u) r ^= Pl[l - 1][j];
            Pl[l][i] = r;
        }
    for (int l = 1; l < NLAYERS; ++l)
        for (int i = 0; i < NQ; ++i) {
            unsigned r = 0;
            for (int j = 0; j < NQ; ++j) if ((Q[i] >> j) & 1u) r ^= Ql[l - 1][j];
            Ql[l][i] = r;
        }
    Plan pl{};
    for (int l = 0; l < NLAYERS; ++l)
        for (int w = 0; w < NQ; ++w) {
            const int b = (NQ - 1) - w;
            unsigned m = 0;
            for (int j = 0; j < NQ; ++j) m |= ((Ql[l][j] >> b) & 1u) << j;  // column b of P^-l
            pl.mask[l][w] = (unsigned short)m;
            pl.row [l][w] = (unsigned short)Pl[l][b];
        }
    for (int w = 0; w < NQ; ++w) pl.zrow[w] = (unsigned short)Pl[NLAYERS][(NQ - 1) - w];
    return pl;
}

constexpr Plan PL = make_plan();

constexpr bool plan_ok() {
    const Plan p = make_plan();
    for (int l = 0; l < NLAYERS; ++l)
        for (int w = 0; w < NQ; ++w) {
            if (p.mask[l][w] == 0) return false;
            if (!(cpop((unsigned)(p.mask[l][w] & p.row[l][w])) & 1)) return false;  // pair must flip the bit
        }
    return true;
}
static_assert(plan_ok(), "bad circuit plan");

// ---------------------------------------------------------------------------
// One fused RY+RZ gate at (layer L, wire W). State: 16 complex amps per lane,
// slot x = (lane<<4)|j. Side s(x) = parity(row & x); amp with s=0 is "|0>".
//   new(x) = cy*old(x) + (s? +sy : -sy)*old(x^m)          (RY)
//   then  *= (cz -/+ i sz) for s=0/1                      (RZ, skipped at L=3)
// ---------------------------------------------------------------------------
template<int L, int W>
__device__ __forceinline__ void apply_gate(float (&sr)[16], float (&si)[16],
                                           float cy, float sy, float cz, float sz,
                                           int lane)
{
    constexpr int m  = PL.mask[L][W];
    constexpr int r  = PL.row [L][W];
    constexpr int mh = m >> 4, ml = m & 15;
    constexpr int rh = r >> 4, rl = r & 15;
    constexpr bool LAST = (L == NLAYERS - 1);

    const int   pl_ = __popc(lane & rh) & 1;
    const float syP = pl_ ? sy : -sy;      // side = pl_ ^ parity(j&rl)
    const float szP = pl_ ? sz : -sz;

    if constexpr (mh == 0) {
        // purely register-local pairs (j, j^ml)
        #pragma unroll
        for (int j = 0; j < 16; ++j) {
            const int k = j ^ ml;
            if (j < k) {
                const float sye = (__popc(j & rl) & 1) ? -syP : syP;
                const float sze = (__popc(j & rl) & 1) ? -szP : szP;
                const float ar = sr[j], ai = si[j];
                const float br_ = sr[k], bi_ = si[k];
                const float t0r = cy * ar + sye * br_;
                const float t0i = cy * ai + sye * bi_;
                const float t1r = cy * br_ - sye * ar;
                const float t1i = cy * bi_ - sye * ai;
                if constexpr (LAST) {
                    sr[j] = t0r; si[j] = t0i; sr[k] = t1r; si[k] = t1i;
                } else {
                    sr[j] = cz * t0r - sze * t0i;  si[j] = cz * t0i + sze * t0r;
                    sr[k] = cz * t1r + sze * t1i;  si[k] = cz * t1i - sze * t1r;
                }
            }
        }
    } else {
        // cross-lane: partner of slot (lane, j) is (lane^mh, j^ml)
        constexpr bool pml = (cpop((unsigned)(ml & rl)) & 1) != 0;  // side(j) vs side(j^ml)
        #pragma unroll
        for (int j = 0; j < 16; ++j) {
            const int k = j ^ ml;
            if (j <= k) {
                const float sye = (__popc(j & rl) & 1) ? -syP : syP;
                const float sze = (__popc(j & rl) & 1) ? -szP : szP;
                const float ar = sr[j], ai = si[j];
                const float br_ = sr[k], bi_ = si[k];
                // pull partner values BEFORE any writes (lockstep SSA copies)
                const float pjr = __shfl_xor(br_, mh, 64);
                const float pji = __shfl_xor(bi_, mh, 64);
                const float t0r = cy * ar + sye * pjr;
                const float t0i = cy * ai + sye * pji;
                if constexpr (LAST) { sr[j] = t0r; si[j] = t0i; }
                else { sr[j] = cz * t0r - sze * t0i; si[j] = cz * t0i + sze * t0r; }
                if (j < k) {
                    const float pkr = __shfl_xor(ar, mh, 64);
                    const float pki = __shfl_xor(ai, mh, 64);
                    const float sye2 = pml ? -sye : sye;
                    const float sze2 = pml ? -sze : sze;
                    const float t1r = cy * br_ + sye2 * pkr;
                    const float t1i = cy * bi_ + sye2 * pki;
                    if constexpr (LAST) { sr[k] = t1r; si[k] = t1i; }
                    else { sr[k] = cz * t1r - sze2 * t1i; si[k] = cz * t1i + sze2 * t1r; }
                }
            }
        }
    }
}

template<int L, int W>
__device__ __forceinline__ void wires(float (&sr)[16], float (&si)[16],
                                      const float (&cy)[NQ], const float (&sy)[NQ],
                                      const float (&cz)[NQ], const float (&sz)[NQ],
                                      int lane)
{
    if constexpr (W < NQ) {
        apply_gate<L, W>(sr, si, cy[W], sy[W], cz[W], sz[W], lane);
        wires<L, W + 1>(sr, si, cy, sy, cz, sz, lane);
    }
}

template<int L>
__device__ __forceinline__ void run_layer(float (&sr)[16], float (&si)[16],
                                          const float* __restrict__ wts, int lane)
{
    float cy[NQ], sy[NQ], cz[NQ], sz[NQ];
    #pragma unroll
    for (int w = 0; w < NQ; ++w) {
        const float hy = 0.5f * wts[(L * NQ + w) * 2 + 0];
        cy[w] = __cosf(hy); sy[w] = __sinf(hy);
        if constexpr (L < NLAYERS - 1) {
            const float hzv = 0.5f * wts[(L * NQ + w) * 2 + 1];
            cz[w] = __cosf(hzv); sz[w] = __sinf(hzv);
        } else { cz[w] = 1.f; sz[w] = 0.f; }   // final-layer RZ is a pure phase: dropped
    }
    wires<L, 0>(sr, si, cy, sy, cz, sz, lane);
}

__global__ __launch_bounds__(64) void qhead_kernel(
    const float* __restrict__ x,    // [B, 768]
    const float* __restrict__ Wr,   // [10, 768]
    const float* __restrict__ br,   // [10]
    const float* __restrict__ wts,  // [4, 10, 2]
    const float* __restrict__ Wo,   // [1, 10]
    const float* __restrict__ bo,   // [1]
    float* __restrict__ out)        // [B]
{
    const int b    = blockIdx.x;
    const int lane = threadIdx.x;   // one wave per batch element

    // ---- embedding angles: alpha_w = tanh(x.Wr_w + br_w)*pi/2 + theta0_w ----
    const float4* xp = reinterpret_cast<const float4*>(x) + (size_t)b * (IDIM / 4);
    const float4  xv0 = xp[lane], xv1 = xp[64 + lane], xv2 = xp[128 + lane];
    float alpha[NQ];
    #pragma unroll
    for (int q = 0; q < NQ; ++q) {
        const float4* wp = reinterpret_cast<const float4*>(Wr) + q * (IDIM / 4);
        const float4  w0 = wp[lane], w1 = wp[64 + lane], w2 = wp[128 + lane];
        float s = xv0.x * w0.x + xv0.y * w0.y + xv0.z * w0.z + xv0.w * w0.w
                + xv1.x * w1.x + xv1.y * w1.y + xv1.z * w1.z + xv1.w * w1.w
                + xv2.x * w2.x + xv2.y * w2.y + xv2.z * w2.z + xv2.w * w2.w;
        #pragma unroll
        for (int o = 32; o; o >>= 1) s += __shfl_xor(s, o, 64);
        const float e = __expf(2.f * (s + br[q]));               // fast tanh
        const float th = (1.f - __fdividef(2.f, e + 1.f)) * 1.57079632679489662f;
        alpha[q] = th + wts[q * 2 + 0];                          // merge layer-0 RY
    }

    // ---- closed-form init: product state after layer-0 RY, with RZ0 phases ----
    float ca[NQ], sa[NQ], hz[NQ];
    #pragma unroll
    for (int q = 0; q < NQ; ++q) {
        ca[q] = __cosf(0.5f * alpha[q]);
        sa[q] = __sinf(0.5f * alpha[q]);
        hz[q] = 0.5f * wts[q * 2 + 1];
    }
    // wires 0..5 <-> lane bits 5..0 ; wires 6..9 <-> j bits 3..0
    float amp_hi = 1.f, ph_hi = 0.f;
    #pragma unroll
    for (int w = 0; w < 6; ++w) {
        const int bit = (lane >> (5 - w)) & 1;
        amp_hi *= bit ? sa[w] : ca[w];
        ph_hi  += bit ? hz[w] : -hz[w];
    }
    float sr[16], si[16];
    #pragma unroll
    for (int j = 0; j < 16; ++j) {
        float a = amp_hi, p = ph_hi;
        a *= (j & 8) ? sa[6] : ca[6];  p += (j & 8) ? hz[6] : -hz[6];
        a *= (j & 4) ? sa[7] : ca[7];  p += (j & 4) ? hz[7] : -hz[7];
        a *= (j & 2) ? sa[8] : ca[8];  p += (j & 2) ? hz[8] : -hz[8];
        a *= (j & 1) ? sa[9] : ca[9];  p += (j & 1) ? hz[9] : -hz[9];
        sr[j] = a * __cosf(p);
        si[j] = a * __sinf(p);
    }

    // ---- layers 1..3 (layer-0 done in init; rings are free relabelings) ----
    run_layer<1>(sr, si, wts, lane);
    run_layer<2>(sr, si, wts, lane);
    run_layer<3>(sr, si, wts, lane);

    // ---- readout: logit = sum_i p_i * sum_w Wo_w*(1-2*parity(zrow_w & i)) ----
    float woS[NQ];
    #pragma unroll
    for (int w = 0; w < NQ; ++w) {
        const int pw = __popc(lane & (PL.zrow[w] >> 4)) & 1;
        woS[w] = pw ? -Wo[w] : Wo[w];
    }
    float acc = 0.f;
    #pragma unroll
    for (int j = 0; j < 16; ++j) {
        float g = 0.f;
        #pragma unroll
        for (int w = 0; w < NQ; ++w)
            g += (__popc(j & (PL.zrow[w] & 15)) & 1) ? -woS[w] : woS[w];
        acc += (sr[j] * sr[j] + si[j] * si[j]) * g;
    }
    #pragma unroll
    for (int o = 32; o; o >>= 1) acc += __shfl_xor(acc, o, 64);
    if (lane == 0) {
        const float logit = acc + bo[0];
        out[b] = __fdividef(1.f, 1.f + __expf(-logit));
    }
}

extern "C" void kernel_launch(void* const* d_in, const int* in_sizes, int n_in,
                              void* d_out, int out_size, void* d_ws, size_t ws_size,
                              hipStream_t stream) {
    const float* x   = (const float*)d_in[0];
    const float* Wr  = (const float*)d_in[1];
    const float* br  = (const float*)d_in[2];
    const float* wts = (const float*)d_in[3];
    const float* Wo  = (const float*)d_in[4];
    const float* bo  = (const float*)d_in[5];
    float* out = (float*)d_out;
    const int B = in_sizes[0] / IDIM;  // 1024

    qhead_kernel<<<B, 64, 0, stream>>>(x, Wr, br, wts, Wo, bo, out);
}

// Round 3
// 20.333 us; speedup vs baseline: 1.4314x; 1.2273x over previous
//
#include <hip/hip_runtime.h>
#include <math.h>

#define NQ      10
#define NSTATE  1024   // 2^NQ
#define NLAYERS 4
#define IDIM    768
#define BLK     256    // 4 waves per batch element; 4 amps per lane

// ---------------------------------------------------------------------------
// Compile-time circuit plan (validated in round 2, absmax = 0).
//
// Index bit b (0..9) <-> wire w = 9-b. One CNOT ring is a GF(2)-linear map P
// on amplitude indices. We never move data for rings; after l rings a gate on
// logical bit b pairs storage slots differing by mask = column b of P^-l, with
// |0>-side parity row = row b of P^l. Readout uses rows of P^4.
// ---------------------------------------------------------------------------
struct Plan {
    unsigned short mask[NLAYERS][NQ];
    unsigned short row [NLAYERS][NQ];
    unsigned short zrow[NQ];
};

constexpr int cpop(unsigned v) { int c = 0; for (; v; v >>= 1) c += (int)(v & 1u); return c; }

constexpr Plan make_plan() {
    unsigned P[NQ] = {}, Q[NQ] = {};
    for (int b = 0; b < NQ; ++b) { P[b] = 1u << b; Q[b] = 1u << b; }
    for (int w = 0; w < NQ; ++w) {
        const int c = (NQ - 1) - w, t = (NQ - 1) - ((w + 1) % NQ);
        P[t] ^= P[c];
    }
    for (int w = NQ - 1; w >= 0; --w) {
        const int c = (NQ - 1) - w, t = (NQ - 1) - ((w + 1) % NQ);
        Q[t] ^= Q[c];
    }
    unsigned Pl[NLAYERS + 1][NQ] = {}, Ql[NLAYERS][NQ] = {};
    for (int b = 0; b < NQ; ++b) { Pl[0][b] = 1u << b; Ql[0][b] = 1u << b; }
    for (int l = 1; l <= NLAYERS; ++l)
        for (int i = 0; i < NQ; ++i) {
            unsigned r = 0;
            for (int j = 0; j < NQ; ++j) if ((P[i] >> j) & 1u) r ^= Pl[l - 1][j];
            Pl[l][i] = r;
        }
    for (int l = 1; l < NLAYERS; ++l)
        for (int i = 0; i < NQ; ++i) {
            unsigned r = 0;
            for (int j = 0; j < NQ; ++j) if ((Q[i] >> j) & 1u) r ^= Ql[l - 1][j];
            Ql[l][i] = r;
        }
    Plan pl{};
    for (int l = 0; l < NLAYERS; ++l)
        for (int w = 0; w < NQ; ++w) {
            const int b = (NQ - 1) - w;
            unsigned m = 0;
            for (int j = 0; j < NQ; ++j) m |= ((Ql[l][j] >> b) & 1u) << j;
            pl.mask[l][w] = (unsigned short)m;
            pl.row [l][w] = (unsigned short)Pl[l][b];
        }
    for (int w = 0; w < NQ; ++w) pl.zrow[w] = (unsigned short)Pl[NLAYERS][(NQ - 1) - w];
    return pl;
}

constexpr Plan PL = make_plan();

constexpr bool plan_ok() {
    const Plan p = make_plan();
    for (int l = 0; l < NLAYERS; ++l)
        for (int w = 0; w < NQ; ++w) {
            if (p.mask[l][w] == 0) return false;
            if (!(cpop((unsigned)(p.mask[l][w] & p.row[l][w])) & 1)) return false;
        }
    return true;
}
static_assert(plan_ok(), "bad circuit plan");

// ---------------------------------------------------------------------------
// Fused RY+RZ at (layer L, wire W). Storage: slot s = (tid<<2)|j, 4 complex
// amps per thread. mask decomposes: m&3 = reg part, (m>>2)&63 = lane part,
// m>>8 = wave part (cross-wave -> LDS exchange, double-buffered, 1 barrier).
//   side(s) = parity(row & s);  new(s) = cy*old(s) + (side? sy:-sy)*old(s^m)
//   RZ (skipped at L=3): r' = cz*t_r - szE*t_i, i' = cz*t_i + szE*t_r,
//   szE = side? sz:-sz.
// ---------------------------------------------------------------------------
template<int L, int W>
__device__ __forceinline__ void apply_gate4(float (&sr)[4], float (&si)[4],
                                            const float* __restrict__ gt,
                                            float (*ex)[NSTATE],
                                            int tid, int& p)
{
    constexpr int m  = PL.mask[L][W];
    constexpr int r  = PL.row [L][W];
    constexpr int mt = m >> 2;   // thread-xor part (lane + wave bits)
    constexpr int ml = m & 3;    // register part
    constexpr int rt = r >> 2, rl = r & 3;
    constexpr bool LAST  = (L == NLAYERS - 1);
    constexpr bool XWAVE = (mt >> 6) != 0;

    const float4 t4 = *reinterpret_cast<const float4*>(gt);
    const float cy = t4.x, sy = t4.y;
    const float cz = LAST ? 1.f : t4.z, sz = LAST ? 0.f : t4.w;
    const int pb = __popc(tid & rt) & 1;

    if constexpr (mt == 0) {
        // register-local pairs (j, j^ml)
        #pragma unroll
        for (int j = 0; j < 4; ++j) {
            const int k = j ^ ml;
            if (j < k) {
                const int sideJ = pb ^ (__popc(j & rl) & 1);
                const float syJ = sideJ ? sy : -sy;
                const float szJ = sideJ ? sz : -sz;
                const float ar = sr[j], ai = si[j], br_ = sr[k], bi_ = si[k];
                const float tjr = cy * ar + syJ * br_, tji = cy * ai + syJ * bi_;
                const float tkr = cy * br_ - syJ * ar, tki = cy * bi_ - syJ * ai;
                if constexpr (LAST) {
                    sr[j] = tjr; si[j] = tji; sr[k] = tkr; si[k] = tki;
                } else {
                    sr[j] = cz * tjr - szJ * tji;  si[j] = cz * tji + szJ * tjr;
                    sr[k] = cz * tkr + szJ * tki;  si[k] = cz * tki - szJ * tkr;
                }
            }
        }
    } else if constexpr (!XWAVE) {
        // cross-lane within wave: partner value via shuffle, update own slots
        float o_r[4], o_i[4];
        #pragma unroll
        for (int jj = 0; jj < 4; ++jj) { o_r[jj] = sr[jj]; o_i[jj] = si[jj]; }
        #pragma unroll
        for (int j = 0; j < 4; ++j) {
            const float pr = __shfl_xor(o_r[j ^ ml], mt, 64);
            const float pi = __shfl_xor(o_i[j ^ ml], mt, 64);
            const int side = pb ^ (__popc(j & rl) & 1);
            const float syE = side ? sy : -sy;
            const float szE = side ? sz : -sz;
            const float tr_ = cy * o_r[j] + syE * pr;
            const float ti_ = cy * o_i[j] + syE * pi;
            if constexpr (LAST) { sr[j] = tr_; si[j] = ti_; }
            else { sr[j] = cz * tr_ - szE * ti_; si[j] = cz * ti_ + szE * tr_; }
        }
    } else {
        // cross-wave: exchange through double-buffered LDS (one barrier)
        float* exR = ex[p * 2 + 0];
        float* exI = ex[p * 2 + 1];
        const int base = tid << 2;
        *reinterpret_cast<float4*>(&exR[base]) = make_float4(sr[0], sr[1], sr[2], sr[3]);
        *reinterpret_cast<float4*>(&exI[base]) = make_float4(si[0], si[1], si[2], si[3]);
        __syncthreads();
        const int pbase = (tid ^ mt) << 2;
        const float4 qr = *reinterpret_cast<const float4*>(&exR[pbase]);
        const float4 qi = *reinterpret_cast<const float4*>(&exI[pbase]);
        const float prr[4] = {qr.x, qr.y, qr.z, qr.w};
        const float pri[4] = {qi.x, qi.y, qi.z, qi.w};
        #pragma unroll
        for (int j = 0; j < 4; ++j) {
            const float pr = prr[j ^ ml], pi = pri[j ^ ml];
            const int side = pb ^ (__popc(j & rl) & 1);
            const float syE = side ? sy : -sy;
            const float szE = side ? sz : -sz;
            const float tr_ = cy * sr[j] + syE * pr;
            const float ti_ = cy * si[j] + syE * pi;
            if constexpr (LAST) { sr[j] = tr_; si[j] = ti_; }
            else { sr[j] = cz * tr_ - szE * ti_; si[j] = cz * ti_ + szE * tr_; }
        }
        p ^= 1;
    }
}

template<int L, int W>
__device__ __forceinline__ void wires4(float (&sr)[4], float (&si)[4],
                                       const float (*sG)[4], float (*ex)[NSTATE],
                                       int tid, int& p)
{
    if constexpr (W < NQ) {
        apply_gate4<L, W>(sr, si, sG[(L - 1) * NQ + W], ex, tid, p);
        wires4<L, W + 1>(sr, si, sG, ex, tid, p);
    }
}

__global__ __launch_bounds__(BLK) void qhead_kernel(
    const float* __restrict__ x,    // [B, 768]
    const float* __restrict__ Wr,   // [10, 768]
    const float* __restrict__ br,   // [10]
    const float* __restrict__ wts,  // [4, 10, 2]
    const float* __restrict__ Wo,   // [1, 10]
    const float* __restrict__ bo,   // [1]
    float* __restrict__ out)        // [B]
{
    __shared__ __align__(16) float sG[3 * NQ][4];   // cy,sy,cz,sz layers 1..3
    __shared__ __align__(16) float sEx[4][NSTATE];  // 2 bufs x (re,im)  16 KB
    __shared__ float sA[NQ], sCa[NQ], sSa[NQ], sHz[NQ], sWo[NQ];
    __shared__ float sRed[4];
    __shared__ float sBo;

    const int tid  = threadIdx.x;
    const int lane = tid & 63;
    const int wv   = tid >> 6;
    const int b    = blockIdx.x;

    // ---- setup: layer trig table + small params (parallel with GEMM) ----
    if (tid < 120) {
        const int g = tid >> 2, c = tid & 3;
        const float h = 0.5f * wts[(NQ + g) * 2 + (c >> 1)];
        sG[g][c] = (c & 1) ? __sinf(h) : __cosf(h);
    } else if (tid < 130) {
        sWo[tid - 120] = Wo[tid - 120];
    } else if (tid < 140) {
        sHz[tid - 130] = 0.5f * wts[(tid - 130) * 2 + 1];
    } else if (tid == 140) {
        sBo = bo[0];
    }

    // ---- embedding GEMM: wave wv handles q = wv, wv+4, wv+8 ----
    const float4* xp = reinterpret_cast<const float4*>(x) + (size_t)b * (IDIM / 4);
    const float4 xv0 = xp[lane], xv1 = xp[64 + lane], xv2 = xp[128 + lane];
    for (int q = wv; q < NQ; q += 4) {
        const float4* wp = reinterpret_cast<const float4*>(Wr) + q * (IDIM / 4);
        const float4 w0 = wp[lane], w1 = wp[64 + lane], w2 = wp[128 + lane];
        float s = xv0.x * w0.x + xv0.y * w0.y + xv0.z * w0.z + xv0.w * w0.w
                + xv1.x * w1.x + xv1.y * w1.y + xv1.z * w1.z + xv1.w * w1.w
                + xv2.x * w2.x + xv2.y * w2.y + xv2.z * w2.z + xv2.w * w2.w;
        #pragma unroll
        for (int o = 32; o; o >>= 1) s += __shfl_xor(s, o, 64);
        if (lane == 0) {
            const float e = __expf(2.f * (s + br[q]));             // fast tanh
            sA[q] = (1.f - __fdividef(2.f, e + 1.f)) * 1.57079632679489662f
                  + wts[q * 2];                                     // + layer-0 RY
        }
    }
    __syncthreads();

    // ---- embedding trig ----
    if (tid < NQ)            sCa[tid]      = __cosf(0.5f * sA[tid]);
    else if (tid < 2 * NQ)   sSa[tid - NQ] = __sinf(0.5f * sA[tid - NQ]);
    __syncthreads();

    // ---- closed-form init (layer 0 RY + RZ phases), slot s = (tid<<2)|j ----
    float ac = 1.f, ph = 0.f;
    #pragma unroll
    for (int w = 0; w < 8; ++w) {                 // wires 0..7 <-> tid bits 7..0
        const int bit = (tid >> (7 - w)) & 1;
        ac *= bit ? sSa[w] : sCa[w];
        ph += bit ? sHz[w] : -sHz[w];
    }
    float sr[4], si[4];
    #pragma unroll
    for (int j = 0; j < 4; ++j) {                 // wires 8,9 <-> j bits 1,0
        const float a  = ac * ((j & 2) ? sSa[8] : sCa[8]) * ((j & 1) ? sSa[9] : sCa[9]);
        const float pp = ph + ((j & 2) ? sHz[8] : -sHz[8]) + ((j & 1) ? sHz[9] : -sHz[9]);
        sr[j] = a * __cosf(pp);
        si[j] = a * __sinf(pp);
    }

    // ---- layers 1..3 ----
    int p = 0;
    wires4<1, 0>(sr, si, sG, sEx, tid, p);
    wires4<2, 0>(sr, si, sG, sEx, tid, p);
    wires4<3, 0>(sr, si, sG, sEx, tid, p);

    // ---- readout: logit = sum_s p_s * sum_w Wo_w*(1-2*parity(zrow_w & s)) ----
    float woT[NQ];
    #pragma unroll
    for (int w = 0; w < NQ; ++w) {
        const int pw = __popc(tid & (PL.zrow[w] >> 2)) & 1;
        woT[w] = pw ? -sWo[w] : sWo[w];
    }
    float acc = 0.f;
    #pragma unroll
    for (int j = 0; j < 4; ++j) {
        float g = 0.f;
        #pragma unroll
        for (int w = 0; w < NQ; ++w)
            g += (__popc(j & (PL.zrow[w] & 3)) & 1) ? -woT[w] : woT[w];
        acc = fmaf(sr[j] * sr[j] + si[j] * si[j], g, acc);
    }
    #pragma unroll
    for (int o = 32; o; o >>= 1) acc += __shfl_xor(acc, o, 64);
    if (lane == 0) sRed[wv] = acc;
    __syncthreads();
    if (tid == 0) {
        const float logit = sRed[0] + sRed[1] + sRed[2] + sRed[3] + sBo;
        out[b] = __fdividef(1.f, 1.f + __expf(-logit));
    }
}

extern "C" void kernel_launch(void* const* d_in, const int* in_sizes, int n_in,
                              void* d_out, int out_size, void* d_ws, size_t ws_size,
                              hipStream_t stream) {
    const float* x   = (const float*)d_in[0];
    const float* Wr  = (const float*)d_in[1];
    const float* br  = (const float*)d_in[2];
    const float* wts = (const float*)d_in[3];
    const float* Wo  = (const float*)d_in[4];
    const float* bo  = (const float*)d_in[5];
    float* out = (float*)d_out;
    const int B = in_sizes[0] / IDIM;  // 1024

    qhead_kernel<<<B, BLK, 0, stream>>>(x, Wr, br, wts, Wo, bo, out);
}

// Round 4
// 18.892 us; speedup vs baseline: 1.5405x; 1.0763x over previous
//
#include <hip/hip_runtime.h>
#include <math.h>

#define NQ 10
#define NLAYERS 4
#define IDIM 768
#define BLK 256

// ---------------------------------------------------------------------------
// Compile-time circuit plan (conventions validated rounds 2-3, absmax = 0).
// Index bit b <-> wire w = 9-b. CNOT ring = GF(2)-linear map P on indices.
// Gate (layer l, wire w): logical mask g = col_{9-w}(Q^l) (Q = P^-1), side
// row r = row_{9-w}(P^l). Storage basis = bit permutation (position p holds
// original bit BASIS[bi][p]); within a layer gates commute, so: do gates
// whose storage mask avoids wave bits {8,9}, transpose once (LDS pass) to
// the next basis, do the rest. RZs of a layer are diagonal -> collapsed to
// one phase pass per layer. Readout rows = rows of P^4 in final basis.
// ---------------------------------------------------------------------------
constexpr int cpop(unsigned v){int c=0;for(;v;v>>=1)c+=(int)(v&1u);return c;}

struct Mats { unsigned Prow[5][NQ]; unsigned Qrow[4][NQ]; };

constexpr Mats make_mats(){
    Mats M{};
    unsigned P[NQ]={},Q[NQ]={};
    for(int b=0;b<NQ;++b){P[b]=1u<<b;Q[b]=1u<<b;}
    for(int w=0;w<NQ;++w){const int c=9-w,t=9-((w+1)%NQ);P[t]^=P[c];}
    for(int w=NQ-1;w>=0;--w){const int c=9-w,t=9-((w+1)%NQ);Q[t]^=Q[c];}
    for(int b=0;b<NQ;++b){M.Prow[0][b]=1u<<b;M.Qrow[0][b]=1u<<b;}
    for(int l=1;l<=4;++l)for(int i=0;i<NQ;++i){
        unsigned r=0;for(int j=0;j<NQ;++j)if((P[i]>>j)&1u)r^=M.Prow[l-1][j];
        M.Prow[l][i]=r;}
    for(int l=1;l<=3;++l)for(int i=0;i<NQ;++i){
        unsigned r=0;for(int j=0;j<NQ;++j)if((Q[i]>>j)&1u)r^=M.Qrow[l-1][j];
        M.Qrow[l][i]=r;}
    return M;
}
constexpr Mats MT = make_mats();

constexpr unsigned qcol(int l,int b){
    unsigned m=0;for(int j=0;j<NQ;++j)m|=((MT.Qrow[l][j]>>b)&1u)<<j;return m;
}

// storage bases: position p (0..9) holds original bit BASIS[bi][p].
// positions 0,1 = register bits (fixed), 2..7 = lane bits, 8,9 = wave bits.
constexpr int BASIS[5][NQ]={
 {0,1,2,3,4,5,6,7,8,9},   // B0: wave = orig {8,9}
 {0,1,2,3,8,5,9,7,4,6},   // B1: wave = orig {4,6}
 {0,1,2,3,8,4,9,6,5,7},   // B2: wave = orig {5,7}
 {0,1,5,7,8,4,9,6,2,3},   // B3a: wave = orig {2,3}
 {0,1,5,7,2,4,3,6,8,9}};  // B3b: wave = orig {8,9}

constexpr unsigned xfm(unsigned g,int bi){
    unsigned m=0;for(int p=0;p<NQ;++p)m|=((g>>BASIS[bi][p])&1u)<<p;return m;
}

// basis index used by gate (layer-1, wire)
constexpr int STAGE[3][NQ]={
 {1,1,0,0,0,0,0,0,0,1},
 {1,2,1,2,1,2,1,1,1,1},
 {3,3,3,4,4,2,2,2,3,2}};

// transposes: K=0: B0->B1, 1: B1->B2, 2: B2->B3a, 3: B3a->B3b
constexpr int TPAIR[4][2]={{0,1},{1,2},{2,3},{3,4}};
constexpr int tsrc(int k,int p){           // old tid bit p = new tid bit tsrc
    const int a=TPAIR[k][0],b=TPAIR[k][1];
    const int orig=BASIS[a][p+2];
    int q=-1;for(int i=0;i<NQ;++i)if(BASIS[b][i]==orig)q=i;
    return q-2;
}

constexpr bool sched_ok(){
    for(int l=1;l<=3;++l)for(int w=0;w<NQ;++w){
        const unsigned g=qcol(l,9-w), r=MT.Prow[l][9-w];
        const int bi=STAGE[l-1][w];
        const unsigned m=xfm(g,bi), rr=xfm(r,bi);
        if(m==0) return false;
        if(m>>8) return false;               // must avoid wave bits
        if(!(cpop(m&rr)&1)) return false;    // pairing must flip the side
    }
    for(int bi=0;bi<5;++bi){
        if(BASIS[bi][0]!=0||BASIS[bi][1]!=1) return false;
        unsigned seen=0;for(int p=0;p<NQ;++p)seen|=1u<<BASIS[bi][p];
        if(seen!=0x3FFu) return false;
    }
    for(int k=0;k<4;++k)for(int p=0;p<8;++p){
        if(tsrc(k,p)<0||tsrc(k,p)>=8) return false;
    }
    return true;
}
static_assert(sched_ok(),"bad schedule");

// rows (side parities) for diagonal passes / readout, pre-split rt/rl
struct RowPlan { unsigned short rt[NQ]; unsigned char rl[NQ]; };
constexpr RowPlan rplan(int l,int bi){
    RowPlan d{};
    for(int w=0;w<NQ;++w){
        const unsigned r=xfm(MT.Prow[l][9-w],bi);
        d.rt[w]=(unsigned short)(r>>2); d.rl[w]=(unsigned char)(r&3);
    }
    return d;
}
constexpr RowPlan DP1=rplan(1,1), DP2=rplan(2,2), ZP=rplan(4,4);

// ---------------------------------------------------------------------------
template<int LM>
__device__ __forceinline__ float lxor(float v){
    if constexpr (LM==0) return v;
    else if constexpr (LM<32)
        return __int_as_float(__builtin_amdgcn_ds_swizzle(__float_as_int(v),(LM<<10)|0x1F));
    else
        return __shfl_xor(v,LM,64);
}

// RY gate at (layer L, wire W) in its scheduled basis. Slot s=(tid<<2)|j.
// new(s) = cy*old(s) + (side(s)? sy : -sy)*old(s^m), side = parity(r & s).
template<int L,int W>
__device__ __forceinline__ void ry(float(&sr)[4],float(&si)[4],
                                   const float2* __restrict__ sG,int tid){
    constexpr unsigned m = xfm(qcol(L,9-W), STAGE[L-1][W]);
    constexpr unsigned r = xfm(MT.Prow[L][9-W], STAGE[L-1][W]);
    constexpr int ml=(int)(m&3u), lm=(int)((m>>2)&63u);
    constexpr int rt=(int)(r>>2), rl=(int)(r&3u);
    const float2 g = sG[(L-1)*NQ+W];
    const float cy=g.x, sy=g.y;
    const int pb=__popc(tid&rt)&1;
    const float syP = pb? sy : -sy;
    if constexpr (lm==0){
        #pragma unroll
        for(int j=0;j<4;++j){
            const int k=j^ml;
            if(j<k){
                const float sJ=((__popc(j&rl)&1)? -syP:syP);
                const float aj=sr[j],ai=si[j],bj=sr[k],bi_=si[k];
                sr[j]=fmaf(sJ,bj,cy*aj);   si[j]=fmaf(sJ,bi_,cy*ai);
                sr[k]=fmaf(-sJ,aj,cy*bj);  si[k]=fmaf(-sJ,ai,cy*bi_);
            }
        }
    } else {
        float o_r[4],o_i[4];
        #pragma unroll
        for(int q=0;q<4;++q){o_r[q]=sr[q];o_i[q]=si[q];}
        #pragma unroll
        for(int j=0;j<4;++j){
            const float pr=lxor<lm>(o_r[j^ml]);
            const float pi=lxor<lm>(o_i[j^ml]);
            const float sE=((__popc(j&rl)&1)? -syP:syP);
            sr[j]=fmaf(sE,pr,cy*o_r[j]);
            si[j]=fmaf(sE,pi,cy*o_i[j]);
        }
    }
}

// basis-change transpose through double-buffered LDS (one barrier)
template<int K>
__device__ __forceinline__ void transp(float(&sr)[4],float(&si)[4],
                                       float (*ex)[1024],int tid,int& pp){
    float* eR=ex[pp*2+0]; float* eI=ex[pp*2+1];
    const int base=tid<<2;
    *reinterpret_cast<float4*>(&eR[base])=make_float4(sr[0],sr[1],sr[2],sr[3]);
    *reinterpret_cast<float4*>(&eI[base])=make_float4(si[0],si[1],si[2],si[3]);
    __syncthreads();
    int ot=0;
    #pragma unroll
    for(int p=0;p<8;++p) ot |= ((tid>>tsrc(K,p))&1)<<p;
    const float4 qr=*reinterpret_cast<const float4*>(&eR[ot<<2]);
    const float4 qi=*reinterpret_cast<const float4*>(&eI[ot<<2]);
    sr[0]=qr.x;sr[1]=qr.y;sr[2]=qr.z;sr[3]=qr.w;
    si[0]=qi.x;si[1]=qi.y;si[2]=qi.z;si[3]=qi.w;
    pp^=1;
}

// one layer's worth of RZ as a single diagonal pass: amp *= exp(i*Phi),
// Phi(s) = sum_w (side_w(s)? +hz_w : -hz_w), via 4-group Walsh butterfly
__device__ __forceinline__ void diag(float(&sr)[4],float(&si)[4],
                                     const RowPlan& dp,
                                     const float* __restrict__ hz,int tid){
    float G[4]={0.f,0.f,0.f,0.f};
    #pragma unroll
    for(int w=0;w<NQ;++w){
        const int pb=__popc(tid&dp.rt[w])&1;
        G[dp.rl[w]] += pb? hz[w] : -hz[w];
    }
    const float ph[4]={G[0]+G[1]+G[2]+G[3], G[0]-G[1]+G[2]-G[3],
                       G[0]+G[1]-G[2]-G[3], G[0]-G[1]-G[2]+G[3]};
    #pragma unroll
    for(int j=0;j<4;++j){
        float s_,c_; __sincosf(ph[j],&s_,&c_);
        const float r0=sr[j],i0=si[j];
        sr[j]=c_*r0-s_*i0;
        si[j]=c_*i0+s_*r0;
    }
}

__global__ __launch_bounds__(BLK) void qhead_kernel(
    const float* __restrict__ x,    // [B, 768]
    const float* __restrict__ Wr,   // [10, 768]
    const float* __restrict__ br,   // [10]
    const float* __restrict__ wts,  // [4, 10, 2]
    const float* __restrict__ Wo,   // [1, 10]
    const float* __restrict__ bo,   // [1]
    float* __restrict__ out)        // [B]
{
    __shared__ __align__(16) float sEx[4][1024];   // 2 bufs x (re,im)  16 KB
    __shared__ __align__(8)  float2 sG2[3*NQ];     // (cy,sy) layers 1..3
    __shared__ float sA[NQ],sCa[NQ],sSa[NQ];
    __shared__ float sHz0[NQ],sHz1[NQ],sHz2[NQ],sWo[NQ];
    __shared__ float sRed[4];
    __shared__ float sBo;

    const int t   =threadIdx.x;
    const int lane=t&63;
    const int wv  =t>>6;
    const int b   =blockIdx.x;

    // ---- setup (parallel with GEMM loads) ----
    if(t<60){
        const int g=t>>1,l=g/NQ+1,w=g%NQ;
        const float h=0.5f*wts[(l*NQ+w)*2];
        reinterpret_cast<float*>(sG2)[t]=(t&1)? __sinf(h):__cosf(h);
    } else if(t<70)  sHz0[t-60]=0.5f*wts[(t-60)*2+1];
    else if(t<80)    sHz1[t-70]=0.5f*wts[((t-70)+NQ)*2+1];
    else if(t<90)    sHz2[t-80]=0.5f*wts[((t-80)+2*NQ)*2+1];
    else if(t<100)   sWo[t-90]=Wo[t-90];
    else if(t==100)  sBo=bo[0];

    // ---- embedding GEMM: wave wv handles q = wv, wv+4, wv+8 ----
    const float4* xp=reinterpret_cast<const float4*>(x)+(size_t)b*(IDIM/4);
    const float4 xv0=xp[lane],xv1=xp[64+lane],xv2=xp[128+lane];
    for(int q=wv;q<NQ;q+=4){
        const float4* wp=reinterpret_cast<const float4*>(Wr)+q*(IDIM/4);
        const float4 w0=wp[lane],w1=wp[64+lane],w2=wp[128+lane];
        float s=xv0.x*w0.x+xv0.y*w0.y+xv0.z*w0.z+xv0.w*w0.w
               +xv1.x*w1.x+xv1.y*w1.y+xv1.z*w1.z+xv1.w*w1.w
               +xv2.x*w2.x+xv2.y*w2.y+xv2.z*w2.z+xv2.w*w2.w;
        #pragma unroll
        for(int o=32;o;o>>=1) s+=__shfl_xor(s,o,64);
        if(lane==0){
            const float e=__expf(2.f*(s+br[q]));                 // fast tanh
            sA[q]=(1.f-__fdividef(2.f,e+1.f))*1.57079632679489662f
                 +wts[q*2];                                       // + layer-0 RY
        }
    }
    __syncthreads();

    if(t<NQ)           sCa[t]   =__cosf(0.5f*sA[t]);
    else if(t<2*NQ)    sSa[t-NQ]=__sinf(0.5f*sA[t-NQ]);
    __syncthreads();

    // ---- closed-form init @B0 (layer-0 RY merged + layer-0 RZ phases) ----
    float ac=1.f,ph=0.f;
    #pragma unroll
    for(int w=0;w<8;++w){                 // wires 0..7 <-> tid bits 7..0
        const int bit=(t>>(7-w))&1;
        ac*=bit? sSa[w]:sCa[w];
        ph+=bit? sHz0[w]:-sHz0[w];
    }
    float sr[4],si[4];
    #pragma unroll
    for(int j=0;j<4;++j){                 // wires 8,9 <-> j bits 1,0
        const float a =ac*((j&2)?sSa[8]:sCa[8])*((j&1)?sSa[9]:sCa[9]);
        const float pp_=ph+((j&2)?sHz0[8]:-sHz0[8])+((j&1)?sHz0[9]:-sHz0[9]);
        float s_,c_; __sincosf(pp_,&s_,&c_);
        sr[j]=a*c_; si[j]=a*s_;
    }

    // ---- layers 1..3: RY gates (wave-free per stage) + transposes + diag ----
    int pp=0;
    ry<1,2>(sr,si,sG2,t); ry<1,3>(sr,si,sG2,t); ry<1,4>(sr,si,sG2,t);
    ry<1,5>(sr,si,sG2,t); ry<1,6>(sr,si,sG2,t); ry<1,7>(sr,si,sG2,t);
    ry<1,8>(sr,si,sG2,t);
    transp<0>(sr,si,sEx,t,pp);
    ry<1,0>(sr,si,sG2,t); ry<1,1>(sr,si,sG2,t); ry<1,9>(sr,si,sG2,t);
    diag(sr,si,DP1,sHz1,t);

    ry<2,0>(sr,si,sG2,t); ry<2,2>(sr,si,sG2,t); ry<2,4>(sr,si,sG2,t);
    ry<2,6>(sr,si,sG2,t); ry<2,7>(sr,si,sG2,t); ry<2,8>(sr,si,sG2,t);
    ry<2,9>(sr,si,sG2,t);
    transp<1>(sr,si,sEx,t,pp);
    ry<2,1>(sr,si,sG2,t); ry<2,3>(sr,si,sG2,t); ry<2,5>(sr,si,sG2,t);
    diag(sr,si,DP2,sHz2,t);

    ry<3,5>(sr,si,sG2,t); ry<3,6>(sr,si,sG2,t); ry<3,7>(sr,si,sG2,t);
    ry<3,9>(sr,si,sG2,t);
    transp<2>(sr,si,sEx,t,pp);
    ry<3,0>(sr,si,sG2,t); ry<3,1>(sr,si,sG2,t); ry<3,2>(sr,si,sG2,t);
    ry<3,8>(sr,si,sG2,t);
    transp<3>(sr,si,sEx,t,pp);
    ry<3,3>(sr,si,sG2,t); ry<3,4>(sr,si,sG2,t);
    // (layer-3 RZ is a pure phase before |.|^2 readout: dropped)

    // ---- readout @B3b: logit = sum_s p_s * g(s), Walsh butterfly for g ----
    float G[4]={0.f,0.f,0.f,0.f};
    #pragma unroll
    for(int w=0;w<NQ;++w){
        const int pb=__popc(t&ZP.rt[w])&1;
        G[ZP.rl[w]] += pb? -sWo[w]:sWo[w];
    }
    const float g0=G[0]+G[1]+G[2]+G[3], g1=G[0]-G[1]+G[2]-G[3];
    const float g2=G[0]+G[1]-G[2]-G[3], g3=G[0]-G[1]-G[2]+G[3];
    float acc=(sr[0]*sr[0]+si[0]*si[0])*g0;
    acc=fmaf(sr[1]*sr[1]+si[1]*si[1],g1,acc);
    acc=fmaf(sr[2]*sr[2]+si[2]*si[2],g2,acc);
    acc=fmaf(sr[3]*sr[3]+si[3]*si[3],g3,acc);
    #pragma unroll
    for(int o=32;o;o>>=1) acc+=__shfl_xor(acc,o,64);
    if(lane==0) sRed[wv]=acc;
    __syncthreads();
    if(t==0){
        const float logit=sRed[0]+sRed[1]+sRed[2]+sRed[3]+sBo;
        out[b]=__fdividef(1.f,1.f+__expf(-logit));
    }
}

extern "C" void kernel_launch(void* const* d_in, const int* in_sizes, int n_in,
                              void* d_out, int out_size, void* d_ws, size_t ws_size,
                              hipStream_t stream) {
    const float* x  =(const float*)d_in[0];
    const float* Wr =(const float*)d_in[1];
    const float* br =(const float*)d_in[2];
    const float* wts=(const float*)d_in[3];
    const float* Wo =(const float*)d_in[4];
    const float* bo =(const float*)d_in[5];
    float* out=(float*)d_out;
    const int B=in_sizes[0]/IDIM;  // 1024

    qhead_kernel<<<B,BLK,0,stream>>>(x,Wr,br,wts,Wo,bo,out);
}